// Round 7
// baseline (190.110 us; speedup 1.0000x reference)
//
#include <hip/hip_runtime.h>
#include <math.h>

#define HID 128
#define INDIM 64
#define NSH 64   // pooled shadow copies

typedef unsigned int uint;
typedef unsigned short ushort;
typedef __attribute__((ext_vector_type(8))) short short8;
typedef __attribute__((ext_vector_type(4))) float f32x4;

static __device__ inline float bf2f(uint h) { return __uint_as_float(h << 16); }
static __device__ inline ushort f2bf(float f) {
    uint u = __float_as_uint(f);
    return (ushort)((u + 0x7fff + ((u >> 16) & 1)) >> 16);  // RNE
}
static __device__ inline uint packbf2(float a, float b) {
    return (uint)f2bf(a) | ((uint)f2bf(b) << 16);
}
static __device__ inline int imin(int a, int b) { return a < b ? a : b; }

static __device__ inline void init8(float* a, uint4 v, float sl) {
    a[0] = bf2f(v.x & 0xffffu) * sl; a[1] = bf2f(v.x >> 16) * sl;
    a[2] = bf2f(v.y & 0xffffu) * sl; a[3] = bf2f(v.y >> 16) * sl;
    a[4] = bf2f(v.z & 0xffffu) * sl; a[5] = bf2f(v.z >> 16) * sl;
    a[6] = bf2f(v.w & 0xffffu) * sl; a[7] = bf2f(v.w >> 16) * sl;
}
static __device__ inline void acc8(float* a, uint4 u, float f) {
    a[0] = fmaf(bf2f(u.x & 0xffffu), f, a[0]); a[1] = fmaf(bf2f(u.x >> 16), f, a[1]);
    a[2] = fmaf(bf2f(u.y & 0xffffu), f, a[2]); a[3] = fmaf(bf2f(u.y >> 16), f, a[3]);
    a[4] = fmaf(bf2f(u.z & 0xffffu), f, a[4]); a[5] = fmaf(bf2f(u.z >> 16), f, a[5]);
    a[6] = fmaf(bf2f(u.w & 0xffffu), f, a[6]); a[7] = fmaf(bf2f(u.w >> 16), f, a[7]);
}
static __device__ inline void init4(float* a, uint2 v, float sl) {
    a[0] = bf2f(v.x & 0xffffu) * sl; a[1] = bf2f(v.x >> 16) * sl;
    a[2] = bf2f(v.y & 0xffffu) * sl; a[3] = bf2f(v.y >> 16) * sl;
}
static __device__ inline void acc4(float* a, uint2 u, float f) {
    a[0] = fmaf(bf2f(u.x & 0xffffu), f, a[0]); a[1] = fmaf(bf2f(u.x >> 16), f, a[1]);
    a[2] = fmaf(bf2f(u.y & 0xffffu), f, a[2]); a[3] = fmaf(bf2f(u.y >> 16), f, a[3]);
}

// ---------------- init + casts + int32/int64 detect ----------------
__global__ __launch_bounds__(256) void k_init_cast(
    const float* __restrict__ x, const float* __restrict__ W1, const float* __restrict__ W2,
    const int* __restrict__ ei,
    uint* __restrict__ xbf, uint* __restrict__ w1t, uint* __restrict__ w2t,
    int* cnt, float* pooledS, int* flag, int N)
{
    int gid = blockIdx.x * 256 + threadIdx.x;
    int stride = gridDim.x * 256;
    if (blockIdx.x == 0) {
        __shared__ int sbad;
        if (threadIdx.x == 0) sbad = 0;
        __syncthreads();
        int bad = (ei[2 * threadIdx.x + 1] != 0) ? 1 : 0;
        if (__any(bad) && (threadIdx.x & 63) == 0) atomicOr(&sbad, 1);
        __syncthreads();
        if (threadIdx.x == 0) *flag = sbad;
    }
    int total = N * 128;  // bf16-pairs of xbf
    for (int i = gid; i < total; i += stride) {
        int n = i >> 7, r = i & 127;
        int b = r >> 5, c2 = r & 31;
        const float* s = x + ((size_t)b * N + n) * 64 + c2 * 2;
        xbf[i] = packbf2(s[0], s[1]);
    }
    if (gid < 128 * 32) { int c = gid >> 5, k2 = gid & 31; w1t[gid] = packbf2(W1[(2 * k2) * 128 + c], W1[(2 * k2 + 1) * 128 + c]); }
    if (gid < 128 * 64) { int c = gid >> 6, k2 = gid & 63; w2t[gid] = packbf2(W2[(2 * k2) * 128 + c], W2[(2 * k2 + 1) * 128 + c]); }
    if (gid < N) cnt[gid] = 0;
    if (gid < NSH * 512) pooledS[gid] = 0.f;
}

// extract src/dst + degree count (fused)
__global__ __launch_bounds__(256) void k_edges(const int* __restrict__ ei, const int* __restrict__ flag,
                                               int* __restrict__ src, int* __restrict__ dst,
                                               int* cnt, int E) {
    int e = blockIdx.x * 256 + threadIdx.x;
    if (e >= E) return;
    int s, d;
    if (*flag) { s = ei[e]; d = ei[(size_t)E + e]; }
    else       { s = ei[2 * (size_t)e]; d = ei[2 * (size_t)E + 2 * (size_t)e]; }
    src[e] = s; dst[e] = d;
    atomicAdd(&cnt[d], 1);
}

// ---------------- parallel single-block scan: 1024 threads, shuffle-scan ----------------
__global__ __launch_bounds__(1024) void k_scan(const int* __restrict__ cnt, int* __restrict__ row_ptr,
                                               float* __restrict__ dis, int* __restrict__ fillcnt, int N) {
    __shared__ int wsum[16];
    int t = threadIdx.x;
    int chunk = (N + 1023) >> 10;
    int lo = t * chunk; if (lo > N) lo = N;
    int hi = lo + chunk; if (hi > N) hi = N;
    int s = 0;
#pragma unroll 4
    for (int i = lo; i < hi; i++) s += cnt[i];
    int lane = t & 63, wid = t >> 6;
    int v = s;
#pragma unroll
    for (int d = 1; d < 64; d <<= 1) {
        int u = __shfl_up(v, d);
        if (lane >= d) v += u;
    }
    if (lane == 63) wsum[wid] = v;
    __syncthreads();
    if (wid == 0) {
        int wv = (lane < 16) ? wsum[lane] : 0;
#pragma unroll
        for (int d = 1; d < 16; d <<= 1) {
            int u = __shfl_up(wv, d);
            if (lane >= d) wv += u;
        }
        if (lane < 16) wsum[lane] = wv;
    }
    __syncthreads();
    int base = (wid > 0 ? wsum[wid - 1] : 0) + (v - s);
    int acc = base;
#pragma unroll 4
    for (int i = lo; i < hi; i++) {
        row_ptr[i] = acc;
        int c = cnt[i];
        acc += c;
        dis[i] = rsqrtf((float)(c + 1));
        fillcnt[i] = 0;
    }
    if (t == 0) row_ptr[N] = wsum[15];
}

// CSR fill; wsrc[p] = dis[src] precomputed
__global__ __launch_bounds__(256) void k_fill(const int* __restrict__ src, const int* __restrict__ dst,
                                              const int* __restrict__ row_ptr, int* fillcnt,
                                              int* __restrict__ col, float* __restrict__ wsrc,
                                              const float* __restrict__ dis, int E) {
    int e = blockIdx.x * 256 + threadIdx.x;
    if (e >= E) return;
    int d = dst[e], s = src[e];
    int p = row_ptr[d] + atomicAdd(&fillcnt[d], 1);
    col[p] = s;
    wsrc[p] = dis[s];
}

// ---------------- layer 1: wave-independent tile, barrier-free, W from global (L1-hot) ----------------
__global__ __launch_bounds__(256, 6) void k_l1(
    const uint* __restrict__ xbf, const int* __restrict__ rp, const int* __restrict__ col,
    const float* __restrict__ wsrc, const float* __restrict__ dis,
    const uint* __restrict__ w1t, const float* __restrict__ b1,
    uint* __restrict__ x1, int ntile)
{
    __shared__ __align__(16) char sXa[4][2048];   // wave-private 16 rows x 128B, swizzled
    int t = threadIdx.x, w = t >> 6, l = t & 63;
    int g = l >> 4, row = l & 15;
    int tile = blockIdx.x * 4 + w;
    if (tile >= ntile) return;
    char* sX = sXa[w];
    const uint2* xr = (const uint2*)xbf;

    int n0 = tile * 4;
    int r0 = rp[n0], r1 = rp[n0 + 1], r2 = rp[n0 + 2], r3 = rp[n0 + 3], r4 = rp[n0 + 4];
    int e0 = r0, e1 = r1, e2 = r2, e3 = r3;
    float dn0 = dis[n0], dn1 = dis[n0 + 1], dn2 = dis[n0 + 2], dn3 = dis[n0 + 3];
    float ac0[4], ac1[4], ac2[4], ac3[4];
    init4(ac0, xr[(size_t)n0 * 64 + l], dn0 * dn0);
    init4(ac1, xr[(size_t)(n0 + 1) * 64 + l], dn1 * dn1);
    init4(ac2, xr[(size_t)(n0 + 2) * 64 + l], dn2 * dn2);
    init4(ac3, xr[(size_t)(n0 + 3) * 64 + l], dn3 * dn3);

#define A2(j) do { \
    int c0_ = col[e##j], c1_ = col[e##j + 1]; \
    float f0_ = wsrc[e##j] * dn##j, f1_ = wsrc[e##j + 1] * dn##j; \
    uint2 u0_ = xr[(size_t)c0_ * 64 + l], u1_ = xr[(size_t)c1_ * 64 + l]; \
    acc4(ac##j, u0_, f0_); acc4(ac##j, u1_, f1_); e##j += 2; } while (0)
#define A1(j) do { \
    int c0_ = col[e##j]; float f0_ = wsrc[e##j] * dn##j; \
    uint2 u0_ = xr[(size_t)c0_ * 64 + l]; acc4(ac##j, u0_, f0_); e##j += 1; } while (0)

    int m = imin(imin(r1 - e0, r2 - e1), imin(r3 - e2, r4 - e3)) >> 1;
    for (int it = 0; it < m; it++) { A2(0); A2(1); A2(2); A2(3); }
    int p01 = imin(r1 - e0, r2 - e1) >> 1;
    for (int it = 0; it < p01; it++) { A2(0); A2(1); }
    int p23 = imin(r3 - e2, r4 - e3) >> 1;
    for (int it = 0; it < p23; it++) { A2(2); A2(3); }
    while (e0 + 1 < r1) A2(0);
    if (e0 < r1) A1(0);
    while (e1 + 1 < r2) A2(1);
    if (e1 < r2) A1(1);
    while (e2 + 1 < r3) A2(2);
    if (e2 < r3) A1(2);
    while (e3 + 1 < r4) A2(3);
    if (e3 < r4) A1(3);
#undef A2
#undef A1

    // write 4 rows (8B each, half-slot swizzle) -- wave-private, no barrier
    {
        uint2 pk;
        pk.x = packbf2(ac0[0], ac0[1]); pk.y = packbf2(ac0[2], ac0[3]);
        int wr = g;
        *(uint2*)(sX + wr * 128 + (((row >> 1) ^ (wr & 7)) << 4) + ((row & 1) << 3)) = pk;
        pk.x = packbf2(ac1[0], ac1[1]); pk.y = packbf2(ac1[2], ac1[3]);
        wr = 4 + g;
        *(uint2*)(sX + wr * 128 + (((row >> 1) ^ (wr & 7)) << 4) + ((row & 1) << 3)) = pk;
        pk.x = packbf2(ac2[0], ac2[1]); pk.y = packbf2(ac2[2], ac2[3]);
        wr = 8 + g;
        *(uint2*)(sX + wr * 128 + (((row >> 1) ^ (wr & 7)) << 4) + ((row & 1) << 3)) = pk;
        pk.x = packbf2(ac3[0], ac3[1]); pk.y = packbf2(ac3[2], ac3[3]);
        wr = 12 + g;
        *(uint2*)(sX + wr * 128 + (((row >> 1) ^ (wr & 7)) << 4) + ((row & 1) << 3)) = pk;
    }
    int ro0 = row * 128 + ((g ^ (row & 7)) << 4);
    int ro1 = row * 128 + (((4 + g) ^ (row & 7)) << 4);
    short8 xf0 = *(const short8*)(sX + ro0);
    short8 xf1 = *(const short8*)(sX + ro1);
    size_t rbase = ((size_t)tile * 16 + row) * 32;
    // W frag: lane(row,g) -> w1t[(q*16+row)*32 + ks*16 + g*4], L1-hot 16KB buffer
#pragma unroll 2
    for (int q = 0; q < 8; q++) {
        const uint* wq = w1t + (q * 16 + row) * 32 + g * 4;
        f32x4 a = {0.f, 0.f, 0.f, 0.f};
        a = __builtin_amdgcn_mfma_f32_16x16x32_bf16(*(const short8*)(wq), xf0, a, 0, 0, 0);
        a = __builtin_amdgcn_mfma_f32_16x16x32_bf16(*(const short8*)(wq + 16), xf1, a, 0, 0, 0);
        float4 bb = *(const float4*)(b1 + q * 16 + g * 4);
        uint2 o;
        o.x = packbf2(fmaxf(a.x + bb.x, 0.f), fmaxf(a.y + bb.y, 0.f));
        o.y = packbf2(fmaxf(a.z + bb.z, 0.f), fmaxf(a.w + bb.w, 0.f));
        ((uint2*)x1)[rbase + q * 4 + g] = o;
    }
}

// ---------------- layer 2: wave-independent tile + MFMA + relu + mean-pool, barrier-free ----------------
__global__ __launch_bounds__(256, 6) void k_l2(
    const uint* __restrict__ x1, const int* __restrict__ rp, const int* __restrict__ col,
    const float* __restrict__ wsrc, const float* __restrict__ dis,
    const uint* __restrict__ w2t, const float* __restrict__ b2,
    float* __restrict__ pooledS, int ntile, float invN)
{
    __shared__ __align__(16) char sXa[4][4096];   // wave-private 16 rows x 256B, swizzled
    int t = threadIdx.x, w = t >> 6, l = t & 63;
    int g = l >> 4, row = l & 15;
    int tile = blockIdx.x * 4 + w;
    if (tile >= ntile) return;
    char* sX = sXa[w];
    const uint4* xr = (const uint4*)x1;

    int n0 = tile * 4;
    int r0 = rp[n0], r1 = rp[n0 + 1], r2 = rp[n0 + 2], r3 = rp[n0 + 3], r4 = rp[n0 + 4];
    int e0 = r0, e1 = r1, e2 = r2, e3 = r3;
    float dn0 = dis[n0], dn1 = dis[n0 + 1], dn2 = dis[n0 + 2], dn3 = dis[n0 + 3];
    float ac0[8], ac1[8], ac2[8], ac3[8];
    init8(ac0, xr[(size_t)n0 * 64 + l], dn0 * dn0);
    init8(ac1, xr[(size_t)(n0 + 1) * 64 + l], dn1 * dn1);
    init8(ac2, xr[(size_t)(n0 + 2) * 64 + l], dn2 * dn2);
    init8(ac3, xr[(size_t)(n0 + 3) * 64 + l], dn3 * dn3);

#define B2(j) do { \
    int c0_ = col[e##j], c1_ = col[e##j + 1]; \
    float f0_ = wsrc[e##j] * dn##j, f1_ = wsrc[e##j + 1] * dn##j; \
    uint4 u0_ = xr[(size_t)c0_ * 64 + l], u1_ = xr[(size_t)c1_ * 64 + l]; \
    acc8(ac##j, u0_, f0_); acc8(ac##j, u1_, f1_); e##j += 2; } while (0)
#define B1(j) do { \
    int c0_ = col[e##j]; float f0_ = wsrc[e##j] * dn##j; \
    uint4 u0_ = xr[(size_t)c0_ * 64 + l]; acc8(ac##j, u0_, f0_); e##j += 1; } while (0)

    int m = imin(imin(r1 - e0, r2 - e1), imin(r3 - e2, r4 - e3)) >> 1;
    for (int it = 0; it < m; it++) { B2(0); B2(1); B2(2); B2(3); }
    int p01 = imin(r1 - e0, r2 - e1) >> 1;
    for (int it = 0; it < p01; it++) { B2(0); B2(1); }
    int p23 = imin(r3 - e2, r4 - e3) >> 1;
    for (int it = 0; it < p23; it++) { B2(2); B2(3); }
    while (e0 + 1 < r1) B2(0);
    if (e0 < r1) B1(0);
    while (e1 + 1 < r2) B2(1);
    if (e1 < r2) B1(1);
    while (e2 + 1 < r3) B2(2);
    if (e2 < r3) B1(2);
    while (e3 + 1 < r4) B2(3);
    if (e3 < r4) B1(3);
#undef B2
#undef B1

    // write 4 rows (16B each, swizzled) -- wave-private
    {
        uint4 pk;
        pk.x = packbf2(ac0[0], ac0[1]); pk.y = packbf2(ac0[2], ac0[3]);
        pk.z = packbf2(ac0[4], ac0[5]); pk.w = packbf2(ac0[6], ac0[7]);
        int wr = g;
        *(uint4*)(sX + wr * 256 + ((row ^ (wr & 7)) << 4)) = pk;
        pk.x = packbf2(ac1[0], ac1[1]); pk.y = packbf2(ac1[2], ac1[3]);
        pk.z = packbf2(ac1[4], ac1[5]); pk.w = packbf2(ac1[6], ac1[7]);
        wr = 4 + g;
        *(uint4*)(sX + wr * 256 + ((row ^ (wr & 7)) << 4)) = pk;
        pk.x = packbf2(ac2[0], ac2[1]); pk.y = packbf2(ac2[2], ac2[3]);
        pk.z = packbf2(ac2[4], ac2[5]); pk.w = packbf2(ac2[6], ac2[7]);
        wr = 8 + g;
        *(uint4*)(sX + wr * 256 + ((row ^ (wr & 7)) << 4)) = pk;
        pk.x = packbf2(ac3[0], ac3[1]); pk.y = packbf2(ac3[2], ac3[3]);
        pk.z = packbf2(ac3[4], ac3[5]); pk.w = packbf2(ac3[6], ac3[7]);
        wr = 12 + g;
        *(uint4*)(sX + wr * 256 + ((row ^ (wr & 7)) << 4)) = pk;
    }
    int ro0 = row * 256 + ((g ^ (row & 7)) << 4);
    int ro1 = row * 256 + (((4 + g) ^ (row & 7)) << 4);
    int ro2 = row * 256 + (((8 + g) ^ (row & 7)) << 4);
    int ro3 = row * 256 + (((12 + g) ^ (row & 7)) << 4);
    short8 xf0 = *(const short8*)(sX + ro0);
    short8 xf1 = *(const short8*)(sX + ro1);
    short8 xf2 = *(const short8*)(sX + ro2);
    short8 xf3 = *(const short8*)(sX + ro3);
    // W frag: lane(row,g) -> w2t[(q*16+row)*64 + ks*16 + g*4], L1-hot 32KB buffer
#pragma unroll 2
    for (int q = 0; q < 8; q++) {
        const uint* wq = w2t + (q * 16 + row) * 64 + g * 4;
        f32x4 a = {0.f, 0.f, 0.f, 0.f};
        a = __builtin_amdgcn_mfma_f32_16x16x32_bf16(*(const short8*)(wq), xf0, a, 0, 0, 0);
        a = __builtin_amdgcn_mfma_f32_16x16x32_bf16(*(const short8*)(wq + 16), xf1, a, 0, 0, 0);
        a = __builtin_amdgcn_mfma_f32_16x16x32_bf16(*(const short8*)(wq + 32), xf2, a, 0, 0, 0);
        a = __builtin_amdgcn_mfma_f32_16x16x32_bf16(*(const short8*)(wq + 48), xf3, a, 0, 0, 0);
        float4 bb = *(const float4*)(b2 + q * 16 + g * 4);
        float v0 = fmaxf(a.x + bb.x, 0.f);
        float v1 = fmaxf(a.y + bb.y, 0.f);
        float v2 = fmaxf(a.z + bb.z, 0.f);
        float v3 = fmaxf(a.w + bb.w, 0.f);
        // sum over the 4 nodes (tile-row bits 2..3) for each batch (bits 0..1)
        v0 += __shfl_xor(v0, 4); v0 += __shfl_xor(v0, 8);
        v1 += __shfl_xor(v1, 4); v1 += __shfl_xor(v1, 8);
        v2 += __shfl_xor(v2, 4); v2 += __shfl_xor(v2, 8);
        v3 += __shfl_xor(v3, 4); v3 += __shfl_xor(v3, 8);
        if ((l & 12) == 0) {
            float* pd = pooledS + (size_t)(tile & (NSH - 1)) * 512 + (l & 3) * 128 + q * 16 + g * 4;
            atomicAdd(pd + 0, v0 * invN);
            atomicAdd(pd + 1, v1 * invN);
            atomicAdd(pd + 2, v2 * invN);
            atomicAdd(pd + 3, v3 * invN);
        }
    }
}

// ---------------- head: parallel shadow reduce + GEMV ----------------
__global__ __launch_bounds__(512) void k_head(const float* __restrict__ pooledS, const float* __restrict__ af,
                                              const float* __restrict__ fcw, const float* __restrict__ fcb,
                                              const float* __restrict__ sig, float* __restrict__ out, int B) {
    __shared__ float pool[512];
    int t = threadIdx.x;
    float s = 0.f;
#pragma unroll 8
    for (int sh = 0; sh < NSH; sh++) s += pooledS[sh * 512 + t];
    pool[t] = s;
    __syncthreads();
    if (t >= B * 16) return;
    int b = t >> 4, o = t & 15;
    float acc = fcb[o];
    for (int c = 0; c < HID; c++) acc = fmaf(pool[b * 128 + c], fcw[c * 16 + o], acc);
    acc = fmaf(af[b], fcw[HID * 16 + o], acc);
    out[t] = acc;
    out[B * 16 + t] = expf(sig[o]);
}

// ---------------- launch ----------------

extern "C" void kernel_launch(void* const* d_in, const int* in_sizes, int n_in,
                              void* d_out, int out_size, void* d_ws, size_t ws_size,
                              hipStream_t stream) {
    const float* x   = (const float*)d_in[0];
    const float* af  = (const float*)d_in[1];
    const int*   ei  = (const int*)d_in[2];
    const float* W1  = (const float*)d_in[3];
    const float* b1  = (const float*)d_in[4];
    const float* W2  = (const float*)d_in[5];
    const float* b2  = (const float*)d_in[6];
    const float* fcw = (const float*)d_in[7];
    const float* fcb = (const float*)d_in[8];
    const float* sig = (const float*)d_in[9];

    int B = in_sizes[1];                 // 4
    int E = in_sizes[2] / 2;             // 320000
    int N = in_sizes[0] / (B * INDIM);   // 20000
    int ntile = N / 4;                   // 5000

    char* p = (char*)d_ws;
    auto alloc = [&](size_t bytes) { void* r = (void*)p; p += (bytes + 255) & ~(size_t)255; return r; };
    int*    cnt     = (int*)alloc((size_t)N * 4);
    int*    fillcnt = (int*)alloc((size_t)N * 4);
    int*    row_ptr = (int*)alloc((size_t)(N + 1) * 4);
    int*    colA    = (int*)alloc((size_t)E * 4);
    int*    srcA    = (int*)alloc((size_t)E * 4);
    int*    dstA    = (int*)alloc((size_t)E * 4);
    float*  wsrcA   = (float*)alloc((size_t)E * 4);
    float*  dis     = (float*)alloc((size_t)N * 4);
    float*  pooledS = (float*)alloc((size_t)NSH * 512 * 4);
    int*    flag    = (int*)alloc(256);
    uint*   xbf     = (uint*)alloc((size_t)N * 128 * 4);      // bf16 [n][4b][64c]
    uint*   x1      = (uint*)alloc((size_t)N * 4 * 64 * 4);   // bf16 [node*4+b][128c]
    uint*   w1t     = (uint*)alloc((size_t)128 * 32 * 4);     // bf16 [128c][64k]
    uint*   w2t     = (uint*)alloc((size_t)128 * 64 * 4);     // bf16 [128c][128k]
    (void)ws_size;

    int gE = (E + 255) / 256;
    int gL = (ntile + 3) / 4;  // one wave per 16-row tile

    k_init_cast<<<2048, 256, 0, stream>>>(x, W1, W2, ei, xbf, w1t, w2t, cnt, pooledS, flag, N);
    k_edges<<<gE, 256, 0, stream>>>(ei, flag, srcA, dstA, cnt, E);
    k_scan<<<1, 1024, 0, stream>>>(cnt, row_ptr, dis, fillcnt, N);
    k_fill<<<gE, 256, 0, stream>>>(srcA, dstA, row_ptr, fillcnt, colA, wsrcA, dis, E);

    k_l1<<<gL, 256, 0, stream>>>(xbf, row_ptr, colA, wsrcA, dis, w1t, b1, x1, ntile);
    k_l2<<<gL, 256, 0, stream>>>(x1, row_ptr, colA, wsrcA, dis, w2t, b2, pooledS, ntile, 1.0f / (float)N);

    k_head<<<1, 512, 0, stream>>>(pooledS, af, fcw, fcb, sig, (float*)d_out, B);
}

// Round 8
// 156.647 us; speedup vs baseline: 1.2136x; 1.2136x over previous
//
#include <hip/hip_runtime.h>
#include <math.h>

#define HID 128
#define INDIM 64
#define NSH 64   // pooled shadow copies

typedef unsigned int uint;
typedef unsigned short ushort;
typedef __attribute__((ext_vector_type(8))) short short8;
typedef __attribute__((ext_vector_type(4))) float f32x4;

static __device__ inline float bf2f(uint h) { return __uint_as_float(h << 16); }
static __device__ inline ushort f2bf(float f) {
    uint u = __float_as_uint(f);
    return (ushort)((u + 0x7fff + ((u >> 16) & 1)) >> 16);  // RNE
}
static __device__ inline uint packbf2(float a, float b) {
    return (uint)f2bf(a) | ((uint)f2bf(b) << 16);
}
static __device__ inline int imin(int a, int b) { return a < b ? a : b; }

static __device__ inline void init4(float* a, uint2 v, float sl) {
    a[0] = bf2f(v.x & 0xffffu) * sl; a[1] = bf2f(v.x >> 16) * sl;
    a[2] = bf2f(v.y & 0xffffu) * sl; a[3] = bf2f(v.y >> 16) * sl;
}
static __device__ inline void acc4(float* a, uint2 u, float f) {
    a[0] = fmaf(bf2f(u.x & 0xffffu), f, a[0]); a[1] = fmaf(bf2f(u.x >> 16), f, a[1]);
    a[2] = fmaf(bf2f(u.y & 0xffffu), f, a[2]); a[3] = fmaf(bf2f(u.y >> 16), f, a[3]);
}

// ---------------- init + casts + int32/int64 detect ----------------
__global__ __launch_bounds__(256) void k_init_cast(
    const float* __restrict__ x, const float* __restrict__ W1, const float* __restrict__ W2,
    const int* __restrict__ ei,
    uint* __restrict__ xbf, uint* __restrict__ w1t, uint* __restrict__ w2t,
    int* cnt, float* pooledS, int* flag, int N)
{
    int gid = blockIdx.x * 256 + threadIdx.x;
    int stride = gridDim.x * 256;
    if (blockIdx.x == 0) {
        __shared__ int sbad;
        if (threadIdx.x == 0) sbad = 0;
        __syncthreads();
        int bad = (ei[2 * threadIdx.x + 1] != 0) ? 1 : 0;
        if (__any(bad) && (threadIdx.x & 63) == 0) atomicOr(&sbad, 1);
        __syncthreads();
        if (threadIdx.x == 0) *flag = sbad;
    }
    int total = N * 128;  // bf16-pairs of xbf
    for (int i = gid; i < total; i += stride) {
        int n = i >> 7, r = i & 127;
        int b = r >> 5, c2 = r & 31;
        const float* s = x + ((size_t)b * N + n) * 64 + c2 * 2;
        xbf[i] = packbf2(s[0], s[1]);
    }
    if (gid < 128 * 32) { int c = gid >> 5, k2 = gid & 31; w1t[gid] = packbf2(W1[(2 * k2) * 128 + c], W1[(2 * k2 + 1) * 128 + c]); }
    if (gid < 128 * 64) { int c = gid >> 6, k2 = gid & 63; w2t[gid] = packbf2(W2[(2 * k2) * 128 + c], W2[(2 * k2 + 1) * 128 + c]); }
    if (gid < N) cnt[gid] = 0;
    if (gid < NSH * 512) pooledS[gid] = 0.f;
}

// extract src/dst + degree count (fused)
__global__ __launch_bounds__(256) void k_edges(const int* __restrict__ ei, const int* __restrict__ flag,
                                               int* __restrict__ src, int* __restrict__ dst,
                                               int* cnt, int E) {
    int e = blockIdx.x * 256 + threadIdx.x;
    if (e >= E) return;
    int s, d;
    if (*flag) { s = ei[e]; d = ei[(size_t)E + e]; }
    else       { s = ei[2 * (size_t)e]; d = ei[2 * (size_t)E + 2 * (size_t)e]; }
    src[e] = s; dst[e] = d;
    atomicAdd(&cnt[d], 1);
}

// ---------------- parallel single-block scan: 1024 threads, shuffle-scan ----------------
__global__ __launch_bounds__(1024) void k_scan(const int* __restrict__ cnt, int* __restrict__ row_ptr,
                                               float* __restrict__ dis, int* __restrict__ fillcnt, int N) {
    __shared__ int wsum[16];
    int t = threadIdx.x;
    int chunk = (N + 1023) >> 10;
    int lo = t * chunk; if (lo > N) lo = N;
    int hi = lo + chunk; if (hi > N) hi = N;
    int s = 0;
#pragma unroll 4
    for (int i = lo; i < hi; i++) s += cnt[i];
    int lane = t & 63, wid = t >> 6;
    int v = s;
#pragma unroll
    for (int d = 1; d < 64; d <<= 1) {
        int u = __shfl_up(v, d);
        if (lane >= d) v += u;
    }
    if (lane == 63) wsum[wid] = v;
    __syncthreads();
    if (wid == 0) {
        int wv = (lane < 16) ? wsum[lane] : 0;
#pragma unroll
        for (int d = 1; d < 16; d <<= 1) {
            int u = __shfl_up(wv, d);
            if (lane >= d) wv += u;
        }
        if (lane < 16) wsum[lane] = wv;
    }
    __syncthreads();
    int base = (wid > 0 ? wsum[wid - 1] : 0) + (v - s);
    int acc = base;
#pragma unroll 4
    for (int i = lo; i < hi; i++) {
        row_ptr[i] = acc;
        int c = cnt[i];
        acc += c;
        dis[i] = rsqrtf((float)(c + 1));
        fillcnt[i] = 0;
    }
    if (t == 0) row_ptr[N] = wsum[15];
}

// CSR fill; wsrc[p] = dis[src] precomputed
__global__ __launch_bounds__(256) void k_fill(const int* __restrict__ src, const int* __restrict__ dst,
                                              const int* __restrict__ row_ptr, int* fillcnt,
                                              int* __restrict__ col, float* __restrict__ wsrc,
                                              const float* __restrict__ dis, int E) {
    int e = blockIdx.x * 256 + threadIdx.x;
    if (e >= E) return;
    int d = dst[e], s = src[e];
    int p = row_ptr[d] + atomicAdd(&fillcnt[d], 1);
    col[p] = s;
    wsrc[p] = dis[s];
}

// ---------------- layer 1 (r6-proven): wave-independent tile, LDS-staged W1, one barrier ----------------
__global__ __launch_bounds__(256, 4) void k_l1(
    const uint* __restrict__ xbf, const int* __restrict__ rp, const int* __restrict__ col,
    const float* __restrict__ wsrc, const float* __restrict__ dis,
    const uint* __restrict__ w1t, const float* __restrict__ b1,
    uint* __restrict__ x1, int ntile)
{
    __shared__ __align__(16) char sW[16384];      // W1T swizzled: 128c x 64k bf16
    __shared__ __align__(16) char sXa[4][2048];   // wave-private 16 rows x 128B
    int t = threadIdx.x, w = t >> 6, l = t & 63;
    int g = l >> 4, row = l & 15;
    for (int i = t; i < 1024; i += 256) {
        int c = i >> 3, ch = i & 7;
        *(uint4*)(sW + c * 128 + ((ch ^ (c & 7)) << 4)) = *(const uint4*)(w1t + c * 32 + ch * 4);
    }
    __syncthreads();  // only barrier in kernel
    int tile = blockIdx.x * 4 + w;
    if (tile >= ntile) return;
    char* sX = sXa[w];
    const uint2* xr = (const uint2*)xbf;

    int n0 = tile * 4;
    int r0 = rp[n0], r1 = rp[n0 + 1], r2 = rp[n0 + 2], r3 = rp[n0 + 3], r4 = rp[n0 + 4];
    int e0 = r0, e1 = r1, e2 = r2, e3 = r3;
    float dn0 = dis[n0], dn1 = dis[n0 + 1], dn2 = dis[n0 + 2], dn3 = dis[n0 + 3];
    float ac0[4], ac1[4], ac2[4], ac3[4];
    init4(ac0, xr[(size_t)n0 * 64 + l], dn0 * dn0);
    init4(ac1, xr[(size_t)(n0 + 1) * 64 + l], dn1 * dn1);
    init4(ac2, xr[(size_t)(n0 + 2) * 64 + l], dn2 * dn2);
    init4(ac3, xr[(size_t)(n0 + 3) * 64 + l], dn3 * dn3);

#define A2(j) do { \
    int c0_ = col[e##j], c1_ = col[e##j + 1]; \
    float f0_ = wsrc[e##j] * dn##j, f1_ = wsrc[e##j + 1] * dn##j; \
    uint2 u0_ = xr[(size_t)c0_ * 64 + l], u1_ = xr[(size_t)c1_ * 64 + l]; \
    acc4(ac##j, u0_, f0_); acc4(ac##j, u1_, f1_); e##j += 2; } while (0)
#define A1(j) do { \
    int c0_ = col[e##j]; float f0_ = wsrc[e##j] * dn##j; \
    uint2 u0_ = xr[(size_t)c0_ * 64 + l]; acc4(ac##j, u0_, f0_); e##j += 1; } while (0)

    int m = imin(imin(r1 - e0, r2 - e1), imin(r3 - e2, r4 - e3)) >> 1;
    for (int it = 0; it < m; it++) { A2(0); A2(1); A2(2); A2(3); }
    int p01 = imin(r1 - e0, r2 - e1) >> 1;
    for (int it = 0; it < p01; it++) { A2(0); A2(1); }
    int p23 = imin(r3 - e2, r4 - e3) >> 1;
    for (int it = 0; it < p23; it++) { A2(2); A2(3); }
    while (e0 + 1 < r1) A2(0);
    if (e0 < r1) A1(0);
    while (e1 + 1 < r2) A2(1);
    if (e1 < r2) A1(1);
    while (e2 + 1 < r3) A2(2);
    if (e2 < r3) A1(2);
    while (e3 + 1 < r4) A2(3);
    if (e3 < r4) A1(3);
#undef A2
#undef A1

    // write 4 rows (8B each, half-slot swizzle) -- wave-private, no barrier
    {
        uint2 pk;
        pk.x = packbf2(ac0[0], ac0[1]); pk.y = packbf2(ac0[2], ac0[3]);
        int wr = g;
        *(uint2*)(sX + wr * 128 + (((row >> 1) ^ (wr & 7)) << 4) + ((row & 1) << 3)) = pk;
        pk.x = packbf2(ac1[0], ac1[1]); pk.y = packbf2(ac1[2], ac1[3]);
        wr = 4 + g;
        *(uint2*)(sX + wr * 128 + (((row >> 1) ^ (wr & 7)) << 4) + ((row & 1) << 3)) = pk;
        pk.x = packbf2(ac2[0], ac2[1]); pk.y = packbf2(ac2[2], ac2[3]);
        wr = 8 + g;
        *(uint2*)(sX + wr * 128 + (((row >> 1) ^ (wr & 7)) << 4) + ((row & 1) << 3)) = pk;
        pk.x = packbf2(ac3[0], ac3[1]); pk.y = packbf2(ac3[2], ac3[3]);
        wr = 12 + g;
        *(uint2*)(sX + wr * 128 + (((row >> 1) ^ (wr & 7)) << 4) + ((row & 1) << 3)) = pk;
    }
    int ro0 = row * 128 + ((g ^ (row & 7)) << 4);
    int ro1 = row * 128 + (((4 + g) ^ (row & 7)) << 4);
    short8 xf0 = *(const short8*)(sX + ro0);
    short8 xf1 = *(const short8*)(sX + ro1);
    size_t rbase = ((size_t)tile * 16 + row) * 32;
#pragma unroll
    for (int q = 0; q < 8; q++) {
        f32x4 a = {0.f, 0.f, 0.f, 0.f};
        const char* wb = sW + q * 2048;
        a = __builtin_amdgcn_mfma_f32_16x16x32_bf16(*(const short8*)(wb + ro0), xf0, a, 0, 0, 0);
        a = __builtin_amdgcn_mfma_f32_16x16x32_bf16(*(const short8*)(wb + ro1), xf1, a, 0, 0, 0);
        float4 bb = *(const float4*)(b1 + q * 16 + g * 4);
        uint2 o;
        o.x = packbf2(fmaxf(a.x + bb.x, 0.f), fmaxf(a.y + bb.y, 0.f));
        o.y = packbf2(fmaxf(a.z + bb.z, 0.f), fmaxf(a.w + bb.w, 0.f));
        ((uint2*)x1)[rbase + q * 4 + g] = o;
    }
}

// ---------------- layer 2 (r5-proven): 4-wave cooperative, dbuf LDS, W-frags in registers ----------------
__global__ __launch_bounds__(256) void k_l2(
    const uint* __restrict__ x1, const int* __restrict__ rp, const int* __restrict__ col,
    const float* __restrict__ wsrc, const float* __restrict__ dis,
    const ushort* __restrict__ w2t, const float* __restrict__ b2,
    float* __restrict__ pooledS, int ntile, float invN)
{
    __shared__ __align__(16) char sX[2 * 4096];   // dbuf: 2 x (16 rows x 256B), XOR-swizzled
    int t = threadIdx.x, w = t >> 6, l = t & 63;
    int g = l >> 4, row = l & 15;
    int ct0 = 2 * w, ct1 = 2 * w + 1;
    short8 wf0[4], wf1[4];
#pragma unroll
    for (int ks = 0; ks < 4; ks++) {
        wf0[ks] = *(const short8*)(w2t + (ct0 * 16 + row) * 128 + ks * 32 + g * 8);
        wf1[ks] = *(const short8*)(w2t + (ct1 * 16 + row) * 128 + ks * 32 + g * 8);
    }
    float4 bb0 = *(const float4*)(b2 + ct0 * 16 + g * 4);
    float4 bb1 = *(const float4*)(b2 + ct1 * 16 + g * 4);
    int wrow = w * 4 + g;
    int woff = wrow * 256 + (((row) ^ (wrow & 7)) << 4);
    int roff[4];
#pragma unroll
    for (int ks = 0; ks < 4; ks++) roff[ks] = row * 256 + (((ks * 4 + g) ^ (row & 7)) << 4);
    const uint4* xr = (const uint4*)x1;
    float p0[4] = {0.f, 0.f, 0.f, 0.f}, p1[4] = {0.f, 0.f, 0.f, 0.f};

    int it = 0;
    for (int tile = blockIdx.x; tile < ntile; tile += gridDim.x, it++) {
        int n = tile * 4 + w;
        float dn = dis[n];
        int beg = rp[n], end = rp[n + 1];
        uint4 v = xr[(size_t)n * 64 + l];
        float sl = dn * dn;
        float a0 = bf2f(v.x & 0xffffu) * sl, a1 = bf2f(v.x >> 16) * sl;
        float a2 = bf2f(v.y & 0xffffu) * sl, a3 = bf2f(v.y >> 16) * sl;
        float a4 = bf2f(v.z & 0xffffu) * sl, a5 = bf2f(v.z >> 16) * sl;
        float a6 = bf2f(v.w & 0xffffu) * sl, a7 = bf2f(v.w >> 16) * sl;
        int e = beg;
        for (; e + 3 < end; e += 4) {
            int s0 = col[e], s1 = col[e + 1], s2 = col[e + 2], s3 = col[e + 3];
            float f0 = wsrc[e] * dn, f1 = wsrc[e + 1] * dn;
            float f2 = wsrc[e + 2] * dn, f3 = wsrc[e + 3] * dn;
            uint4 u0 = xr[(size_t)s0 * 64 + l], u1 = xr[(size_t)s1 * 64 + l];
            uint4 u2 = xr[(size_t)s2 * 64 + l], u3 = xr[(size_t)s3 * 64 + l];
            a0 = fmaf(bf2f(u0.x & 0xffffu), f0, a0); a1 = fmaf(bf2f(u0.x >> 16), f0, a1);
            a2 = fmaf(bf2f(u0.y & 0xffffu), f0, a2); a3 = fmaf(bf2f(u0.y >> 16), f0, a3);
            a4 = fmaf(bf2f(u0.z & 0xffffu), f0, a4); a5 = fmaf(bf2f(u0.z >> 16), f0, a5);
            a6 = fmaf(bf2f(u0.w & 0xffffu), f0, a6); a7 = fmaf(bf2f(u0.w >> 16), f0, a7);
            a0 = fmaf(bf2f(u1.x & 0xffffu), f1, a0); a1 = fmaf(bf2f(u1.x >> 16), f1, a1);
            a2 = fmaf(bf2f(u1.y & 0xffffu), f1, a2); a3 = fmaf(bf2f(u1.y >> 16), f1, a3);
            a4 = fmaf(bf2f(u1.z & 0xffffu), f1, a4); a5 = fmaf(bf2f(u1.z >> 16), f1, a5);
            a6 = fmaf(bf2f(u1.w & 0xffffu), f1, a6); a7 = fmaf(bf2f(u1.w >> 16), f1, a7);
            a0 = fmaf(bf2f(u2.x & 0xffffu), f2, a0); a1 = fmaf(bf2f(u2.x >> 16), f2, a1);
            a2 = fmaf(bf2f(u2.y & 0xffffu), f2, a2); a3 = fmaf(bf2f(u2.y >> 16), f2, a3);
            a4 = fmaf(bf2f(u2.z & 0xffffu), f2, a4); a5 = fmaf(bf2f(u2.z >> 16), f2, a5);
            a6 = fmaf(bf2f(u2.w & 0xffffu), f2, a6); a7 = fmaf(bf2f(u2.w >> 16), f2, a7);
            a0 = fmaf(bf2f(u3.x & 0xffffu), f3, a0); a1 = fmaf(bf2f(u3.x >> 16), f3, a1);
            a2 = fmaf(bf2f(u3.y & 0xffffu), f3, a2); a3 = fmaf(bf2f(u3.y >> 16), f3, a3);
            a4 = fmaf(bf2f(u3.z & 0xffffu), f3, a4); a5 = fmaf(bf2f(u3.z >> 16), f3, a5);
            a6 = fmaf(bf2f(u3.w & 0xffffu), f3, a6); a7 = fmaf(bf2f(u3.w >> 16), f3, a7);
        }
        for (; e < end; e++) {
            int s = col[e];
            float f = wsrc[e] * dn;
            uint4 u = xr[(size_t)s * 64 + l];
            a0 = fmaf(bf2f(u.x & 0xffffu), f, a0); a1 = fmaf(bf2f(u.x >> 16), f, a1);
            a2 = fmaf(bf2f(u.y & 0xffffu), f, a2); a3 = fmaf(bf2f(u.y >> 16), f, a3);
            a4 = fmaf(bf2f(u.z & 0xffffu), f, a4); a5 = fmaf(bf2f(u.z >> 16), f, a5);
            a6 = fmaf(bf2f(u.w & 0xffffu), f, a6); a7 = fmaf(bf2f(u.w >> 16), f, a7);
        }
        char* wb = sX + (it & 1) * 4096;
        uint4 pk;
        pk.x = packbf2(a0, a1); pk.y = packbf2(a2, a3);
        pk.z = packbf2(a4, a5); pk.w = packbf2(a6, a7);
        *(uint4*)(wb + woff) = pk;
        __syncthreads();
        short8 xf[4];
#pragma unroll
        for (int ks = 0; ks < 4; ks++) xf[ks] = *(const short8*)(wb + roff[ks]);
        f32x4 acc0 = {0.f, 0.f, 0.f, 0.f}, acc1 = {0.f, 0.f, 0.f, 0.f};
#pragma unroll
        for (int ks = 0; ks < 4; ks++) {
            acc0 = __builtin_amdgcn_mfma_f32_16x16x32_bf16(wf0[ks], xf[ks], acc0, 0, 0, 0);
            acc1 = __builtin_amdgcn_mfma_f32_16x16x32_bf16(wf1[ks], xf[ks], acc1, 0, 0, 0);
        }
        p0[0] += fmaxf(acc0.x + bb0.x, 0.f); p0[1] += fmaxf(acc0.y + bb0.y, 0.f);
        p0[2] += fmaxf(acc0.z + bb0.z, 0.f); p0[3] += fmaxf(acc0.w + bb0.w, 0.f);
        p1[0] += fmaxf(acc1.x + bb1.x, 0.f); p1[1] += fmaxf(acc1.y + bb1.y, 0.f);
        p1[2] += fmaxf(acc1.z + bb1.z, 0.f); p1[3] += fmaxf(acc1.w + bb1.w, 0.f);
    }
    // rows with same batch b = row&3 live in lanes l, l^4, l^8
#pragma unroll
    for (int i = 0; i < 4; i++) {
        p0[i] += __shfl_xor(p0[i], 4); p0[i] += __shfl_xor(p0[i], 8);
        p1[i] += __shfl_xor(p1[i], 4); p1[i] += __shfl_xor(p1[i], 8);
    }
    if ((l & 12) == 0) {
        int b = l & 3;
        float* pd = pooledS + (size_t)(blockIdx.x & (NSH - 1)) * 512 + b * 128;
#pragma unroll
        for (int i = 0; i < 4; i++) {
            atomicAdd(&pd[ct0 * 16 + g * 4 + i], p0[i] * invN);
            atomicAdd(&pd[ct1 * 16 + g * 4 + i], p1[i] * invN);
        }
    }
}

// ---------------- head: parallel shadow reduce + GEMV ----------------
__global__ __launch_bounds__(512) void k_head(const float* __restrict__ pooledS, const float* __restrict__ af,
                                              const float* __restrict__ fcw, const float* __restrict__ fcb,
                                              const float* __restrict__ sig, float* __restrict__ out, int B) {
    __shared__ float pool[512];
    int t = threadIdx.x;
    float s = 0.f;
#pragma unroll 8
    for (int sh = 0; sh < NSH; sh++) s += pooledS[sh * 512 + t];
    pool[t] = s;
    __syncthreads();
    if (t >= B * 16) return;
    int b = t >> 4, o = t & 15;
    float acc = fcb[o];
    for (int c = 0; c < HID; c++) acc = fmaf(pool[b * 128 + c], fcw[c * 16 + o], acc);
    acc = fmaf(af[b], fcw[HID * 16 + o], acc);
    out[t] = acc;
    out[B * 16 + t] = expf(sig[o]);
}

// ---------------- launch ----------------

extern "C" void kernel_launch(void* const* d_in, const int* in_sizes, int n_in,
                              void* d_out, int out_size, void* d_ws, size_t ws_size,
                              hipStream_t stream) {
    const float* x   = (const float*)d_in[0];
    const float* af  = (const float*)d_in[1];
    const int*   ei  = (const int*)d_in[2];
    const float* W1  = (const float*)d_in[3];
    const float* b1  = (const float*)d_in[4];
    const float* W2  = (const float*)d_in[5];
    const float* b2  = (const float*)d_in[6];
    const float* fcw = (const float*)d_in[7];
    const float* fcb = (const float*)d_in[8];
    const float* sig = (const float*)d_in[9];

    int B = in_sizes[1];                 // 4
    int E = in_sizes[2] / 2;             // 320000
    int N = in_sizes[0] / (B * INDIM);   // 20000
    int ntile = N / 4;                   // 5000

    char* p = (char*)d_ws;
    auto alloc = [&](size_t bytes) { void* r = (void*)p; p += (bytes + 255) & ~(size_t)255; return r; };
    int*    cnt     = (int*)alloc((size_t)N * 4);
    int*    fillcnt = (int*)alloc((size_t)N * 4);
    int*    row_ptr = (int*)alloc((size_t)(N + 1) * 4);
    int*    colA    = (int*)alloc((size_t)E * 4);
    int*    srcA    = (int*)alloc((size_t)E * 4);
    int*    dstA    = (int*)alloc((size_t)E * 4);
    float*  wsrcA   = (float*)alloc((size_t)E * 4);
    float*  dis     = (float*)alloc((size_t)N * 4);
    float*  pooledS = (float*)alloc((size_t)NSH * 512 * 4);
    int*    flag    = (int*)alloc(256);
    uint*   xbf     = (uint*)alloc((size_t)N * 128 * 4);      // bf16 [n][4b][64c]
    uint*   x1      = (uint*)alloc((size_t)N * 4 * 64 * 4);   // bf16 [n*4+b][128c]
    uint*   w1t     = (uint*)alloc((size_t)128 * 32 * 4);     // bf16 [128c][64k]
    uint*   w2t     = (uint*)alloc((size_t)128 * 64 * 4);     // bf16 [128c][128k]
    (void)ws_size;

    int gE = (E + 255) / 256;
    int gL1 = (ntile + 3) / 4;  // one wave per 16-row tile (k_l1)

    k_init_cast<<<2048, 256, 0, stream>>>(x, W1, W2, ei, xbf, w1t, w2t, cnt, pooledS, flag, N);
    k_edges<<<gE, 256, 0, stream>>>(ei, flag, srcA, dstA, cnt, E);
    k_scan<<<1, 1024, 0, stream>>>(cnt, row_ptr, dis, fillcnt, N);
    k_fill<<<gE, 256, 0, stream>>>(srcA, dstA, row_ptr, fillcnt, colA, wsrcA, dis, E);

    k_l1<<<gL1, 256, 0, stream>>>(xbf, row_ptr, colA, wsrcA, dis, w1t, b1, x1, ntile);
    k_l2<<<2048, 256, 0, stream>>>(x1, row_ptr, colA, wsrcA, dis, (const ushort*)w2t, b2, pooledS, ntile, 1.0f / (float)N);

    k_head<<<1, 512, 0, stream>>>(pooledS, af, fcw, fcb, sig, (float*)d_out, B);
}